// Round 2
// 2577.334 us; speedup vs baseline: 1.1838x; 1.1838x over previous
//
#include <hip/hip_runtime.h>

typedef unsigned short u16;
typedef unsigned int u32;
typedef unsigned long long u64;

typedef short bf16x8 __attribute__((ext_vector_type(8)));
typedef float f32x4 __attribute__((ext_vector_type(4)));
typedef u32 u32x4 __attribute__((ext_vector_type(4)));

#define NB 64
#define NS 512
#define ND 768
#define NH 384
#define NT_OUT 22
#define S2 272           // materialized xg time extent (n[b] <= 256 < 272)
#define NG 1536          // 4*H
#define MGEMM (NB*S2)    // 17408
#define MAGIC 0x5A5AA5A5u

__device__ __forceinline__ u16 f2b(float f) {
    u32 u = __float_as_uint(f);
    u32 r = (u + 0x7fffu + ((u >> 16) & 1u)) >> 16;
    return (u16)r;
}
__device__ __forceinline__ float b2f(u16 s) { return __uint_as_float(((u32)s) << 16); }

__device__ __forceinline__ float sigm(float x) {
    return __builtin_amdgcn_rcpf(1.f + __expf(-x));
}
__device__ __forceinline__ float tanh_(float x) {
    return 1.f - 2.f * __builtin_amdgcn_rcpf(1.f + __expf(2.f * x));
}

__device__ __forceinline__ void gl_lds16(const void* g, void* l) {
    __builtin_amdgcn_global_load_lds(
        (const __attribute__((address_space(1))) unsigned int*)g,
        (__attribute__((address_space(3))) unsigned int*)l, 16, 0, 0);
}

// ---------------- sc0 / sc1 access helpers ----------------
// sc0      : bypass L1, meet at this XCD's L2 (nt = no L1 allocate on loads)
// sc0 sc1  : bypass L1+L2, meet at device coherence point (Infinity Cache)
__device__ __forceinline__ u32 ld_sc0(const int* p) {
    u32 v;
    asm volatile("global_load_dword %0, %1, off sc0 nt\n\t"
                 "s_waitcnt vmcnt(0)"
                 : "=&v"(v) : "v"(p) : "memory");
    return v;
}
__device__ __forceinline__ u32 ld_sc01(const int* p) {
    u32 v;
    asm volatile("global_load_dword %0, %1, off sc0 sc1\n\t"
                 "s_waitcnt vmcnt(0)"
                 : "=&v"(v) : "v"(p) : "memory");
    return v;
}
__device__ __forceinline__ void st_sc0(int* p, u32 v) {
    asm volatile("global_store_dword %0, %1, off sc0" :: "v"(p), "v"(v) : "memory");
}
__device__ __forceinline__ void st_sc01(int* p, u32 v) {
    asm volatile("global_store_dword %0, %1, off sc0 sc1" :: "v"(p), "v"(v) : "memory");
}

// 6x dwordx4 of one sibling h-chunk (per lane: 3 k-slices x 8 tagged words), no wait
__device__ __forceinline__ void ld6_nw(bool fast, const u32* p,
        u32x4& A, u32x4& B, u32x4& C, u32x4& D, u32x4& E, u32x4& F) {
    if (fast)
        asm volatile(
            "global_load_dwordx4 %0, %6, off sc0 nt\n\t"
            "global_load_dwordx4 %1, %6, off offset:16 sc0 nt\n\t"
            "global_load_dwordx4 %2, %6, off offset:128 sc0 nt\n\t"
            "global_load_dwordx4 %3, %6, off offset:144 sc0 nt\n\t"
            "global_load_dwordx4 %4, %6, off offset:256 sc0 nt\n\t"
            "global_load_dwordx4 %5, %6, off offset:272 sc0 nt"
            : "=&v"(A), "=&v"(B), "=&v"(C), "=&v"(D), "=&v"(E), "=&v"(F)
            : "v"(p) : "memory");
    else
        asm volatile(
            "global_load_dwordx4 %0, %6, off sc0 sc1\n\t"
            "global_load_dwordx4 %1, %6, off offset:16 sc0 sc1\n\t"
            "global_load_dwordx4 %2, %6, off offset:128 sc0 sc1\n\t"
            "global_load_dwordx4 %3, %6, off offset:144 sc0 sc1\n\t"
            "global_load_dwordx4 %4, %6, off offset:256 sc0 sc1\n\t"
            "global_load_dwordx4 %5, %6, off offset:272 sc0 sc1"
            : "=&v"(A), "=&v"(B), "=&v"(C), "=&v"(D), "=&v"(E), "=&v"(F)
            : "v"(p) : "memory");
}
// same, with internal wait (retry path)
__device__ __forceinline__ void ld6_wt(bool fast, const u32* p,
        u32x4& A, u32x4& B, u32x4& C, u32x4& D, u32x4& E, u32x4& F) {
    if (fast)
        asm volatile(
            "global_load_dwordx4 %0, %6, off sc0 nt\n\t"
            "global_load_dwordx4 %1, %6, off offset:16 sc0 nt\n\t"
            "global_load_dwordx4 %2, %6, off offset:128 sc0 nt\n\t"
            "global_load_dwordx4 %3, %6, off offset:144 sc0 nt\n\t"
            "global_load_dwordx4 %4, %6, off offset:256 sc0 nt\n\t"
            "global_load_dwordx4 %5, %6, off offset:272 sc0 nt\n\t"
            "s_waitcnt vmcnt(0)"
            : "=&v"(A), "=&v"(B), "=&v"(C), "=&v"(D), "=&v"(E), "=&v"(F)
            : "v"(p) : "memory");
    else
        asm volatile(
            "global_load_dwordx4 %0, %6, off sc0 sc1\n\t"
            "global_load_dwordx4 %1, %6, off offset:16 sc0 sc1\n\t"
            "global_load_dwordx4 %2, %6, off offset:128 sc0 sc1\n\t"
            "global_load_dwordx4 %3, %6, off offset:144 sc0 sc1\n\t"
            "global_load_dwordx4 %4, %6, off offset:256 sc0 sc1\n\t"
            "global_load_dwordx4 %5, %6, off offset:272 sc0 sc1\n\t"
            "s_waitcnt vmcnt(0)"
            : "=&v"(A), "=&v"(B), "=&v"(C), "=&v"(D), "=&v"(E), "=&v"(F)
            : "v"(p) : "memory");
}
__device__ __forceinline__ void st8(bool fast, u32* p, u32x4 lo, u32x4 hi) {
    if (fast)
        asm volatile("global_store_dwordx4 %0, %1, off sc0\n\t"
                     "global_store_dwordx4 %0, %2, off offset:16 sc0"
                     :: "v"(p), "v"(lo), "v"(hi) : "memory");
    else
        asm volatile("global_store_dwordx4 %0, %1, off sc0 sc1\n\t"
                     "global_store_dwordx4 %0, %2, off offset:16 sc0 sc1"
                     :: "v"(p), "v"(lo), "v"(hi) : "memory");
}
__device__ __forceinline__ void wait_vm6() {
    __builtin_amdgcn_sched_barrier(0);
    asm volatile("s_waitcnt vmcnt(6)" ::: "memory");
    __builtin_amdgcn_sched_barrier(0);
}
__device__ __forceinline__ void wait_vm0() {
    __builtin_amdgcn_sched_barrier(0);
    asm volatile("s_waitcnt vmcnt(0)" ::: "memory");
    __builtin_amdgcn_sched_barrier(0);
}
// LDS-only barrier: no vmcnt(0) drain (global exchange is self-validating)
__device__ __forceinline__ void ldsbar() {
    asm volatile("s_waitcnt lgkmcnt(0)" ::: "memory");
    __builtin_amdgcn_s_barrier();
    __builtin_amdgcn_sched_barrier(0);
}

// sum of low-16 tags of 24 words; tags are monotone (stale in {0, T-3}) so
// sum == 24*T  <=>  all 24 words carry tag T.
__device__ __forceinline__ u32 sum6(const u32x4& a, const u32x4& b, const u32x4& c,
                                    const u32x4& d, const u32x4& e, const u32x4& f) {
    u32 s = (a[0] & 0xffffu) + (a[1] & 0xffffu) + (a[2] & 0xffffu) + (a[3] & 0xffffu);
    s += (b[0] & 0xffffu) + (b[1] & 0xffffu) + (b[2] & 0xffffu) + (b[3] & 0xffffu);
    s += (c[0] & 0xffffu) + (c[1] & 0xffffu) + (c[2] & 0xffffu) + (c[3] & 0xffffu);
    s += (d[0] & 0xffffu) + (d[1] & 0xffffu) + (d[2] & 0xffffu) + (d[3] & 0xffffu);
    s += (e[0] & 0xffffu) + (e[1] & 0xffffu) + (e[2] & 0xffffu) + (e[3] & 0xffffu);
    s += (f[0] & 0xffffu) + (f[1] & 0xffffu) + (f[2] & 0xffffu) + (f[3] & 0xffffu);
    return s;
}
// pack 8 tagged words (h in high 16 bits) -> bf16x8 fragment
__device__ __forceinline__ bf16x8 packf(const u32x4& lo, const u32x4& hi) {
    union { u32 q[4]; bf16x8 v; } U;
    U.q[0] = __builtin_amdgcn_perm(lo[1], lo[0], 0x07060302u);
    U.q[1] = __builtin_amdgcn_perm(lo[3], lo[2], 0x07060302u);
    U.q[2] = __builtin_amdgcn_perm(hi[1], hi[0], 0x07060302u);
    U.q[3] = __builtin_amdgcn_perm(hi[3], hi[2], 0x07060302u);
    return U.v;
}

// ---------------- prep: align/gather -> embeds bf16 [64][272][768] ----------------
__global__ void k_prep(const float* __restrict__ hidden, const int* __restrict__ start_ids,
                       const int* __restrict__ masks, u16* __restrict__ embeds) {
    int b = blockIdx.x >> 2;
    int quarter = blockIdx.x & 3;
    int tid = threadIdx.x;
    __shared__ int red[256];
    int cn = 0, cm = 0;
    for (int s = tid; s < NS; s += 256) {
        cn += (start_ids[b * NS + s] >= 0) ? 1 : 0;
        cm += (masks[b * NS + s] != 0) ? 1 : 0;
    }
    red[tid] = cn + (cm << 16);
    __syncthreads();
    #pragma unroll
    for (int off = 128; off > 0; off >>= 1) {
        if (tid < off) red[tid] += red[tid + off];
        __syncthreads();
    }
    int n = red[0] & 0xffff;
    int slen = red[0] >> 16;
    n = min(max(n, 1), NS);
    int last = start_ids[b * NS + n - 1];
    for (int t = quarter * 68; t < quarter * 68 + 68; ++t) {
        int idx;
        if (t == 0) idx = 0;
        else if (t < n) idx = start_ids[b * NS + t] - 1;
        else if (t == n) idx = last;
        else idx = 0;
        idx = min(max(idx, 0), NS - 1);
        bool keep = t < slen;
        const float* src = hidden + ((size_t)b * NS + idx) * ND;
        u16* dst = embeds + ((size_t)b * S2 + t) * ND;
        if (tid < 192) {
            float4 v = keep ? *(const float4*)(src + tid * 4) : make_float4(0.f, 0.f, 0.f, 0.f);
            union { u16 u[4]; uint2 q; } pk;
            pk.u[0] = f2b(v.x); pk.u[1] = f2b(v.y); pk.u[2] = f2b(v.z); pk.u[3] = f2b(v.w);
            *(uint2*)(dst + tid * 4) = pk.q;
        }
    }
}

// ---------------- weights: cast W_ih (cat) to bf16, bias sums, h0 cast ----------------
__global__ void k_weights(const float* __restrict__ wf, const float* __restrict__ wb,
                          const float* __restrict__ bihf, const float* __restrict__ bhhf,
                          const float* __restrict__ bihb, const float* __restrict__ bhhb,
                          const float* __restrict__ h0,
                          u16* __restrict__ wihcat, float* __restrict__ biascat,
                          u16* __restrict__ h0buf) {
    int i0 = blockIdx.x * blockDim.x + threadIdx.x;
    int NTH = gridDim.x * blockDim.x;
    for (size_t i = i0; i < (size_t)2 * NG * ND; i += NTH) {
        size_t nrow = i / ND, k = i - nrow * ND;
        float v = (nrow < NG) ? wf[nrow * ND + k] : wb[(nrow - NG) * ND + k];
        wihcat[i] = f2b(v);
    }
    for (int i = i0; i < 2 * NG; i += NTH)
        biascat[i] = (i < NG) ? bihf[i] + bhhf[i] : bihb[i - NG] + bhhb[i - NG];
    for (int i = i0; i < 2 * NB * NH; i += NTH) h0buf[i] = f2b(h0[i]);
}

// ---------------- pack Whh into MFMA B-fragment order ----------------
// layout: [d][qc][w][nt][ks][lane][8]  (d:2, qc:4 j-chunk, w:4 gate, nt:6, ks:12)
__global__ void k_packwhh(const float* __restrict__ whhf, const float* __restrict__ whhb,
                          u16* __restrict__ pack) {
    int ft = blockIdx.x * 256 + threadIdx.x;
    if (ft >= 2 * 4 * 4 * 6 * 12 * 64) return;
    int lane = ft & 63;
    int grp = ft >> 6;
    int ks = grp % 12; grp /= 12;
    int nt = grp % 6;  grp /= 6;
    int w  = grp & 3;  grp >>= 2;
    int qc = grp & 3;
    int d  = grp >> 2;
    const float* W = d ? whhb : whhf;
    int col = w * NH + qc * 96 + nt * 16 + (lane & 15);
    int k0 = ks * 32 + (lane >> 4) * 8;
    u16* dst = pack + (size_t)ft * 8;
    #pragma unroll
    for (int e = 0; e < 8; e++) dst[e] = f2b(W[(size_t)col * NH + k0 + e]);
}

// ---------------- GEMM: xg[d][b][t<272][1536] (bf16) = embeds @ WihcatT + bias ----------------
__launch_bounds__(256, 2)
__global__ void k_gemm(const u16* __restrict__ A, const u16* __restrict__ Bw,
                       const float* __restrict__ biascat, u16* __restrict__ xg) {
    __shared__ u16 As[128 * 32];
    __shared__ u16 Bs[128 * 32];
    int tid = threadIdx.x;
    int lane = tid & 63, wid = tid >> 6;
    int l15 = lane & 15, q4 = lane >> 4;
    int bn = blockIdx.x;   // 24 tiles of N=3072
    int bm = blockIdx.y;   // 136 tiles of M=17408
    int wm = (wid >> 1) * 64, wn = (wid & 1) * 64;
    f32x4 acc[4][4] = {};
    for (int k0 = 0; k0 < ND; k0 += 32) {
        #pragma unroll
        for (int j = 0; j < 2; j++) {
            int fl = tid + j * 256;
            int row = fl >> 2, cb = fl & 3;
            const u16* ga = A + (size_t)(bm * 128 + row) * ND + k0 + cb * 8;
            gl_lds16(ga, &As[(size_t)(wid * 64 + j * 256) * 8]);
            const u16* gb = Bw + (size_t)(bn * 128 + row) * ND + k0 + cb * 8;
            gl_lds16(gb, &Bs[(size_t)(wid * 64 + j * 256) * 8]);
        }
        __syncthreads();
        bf16x8 af[4], bf[4];
        #pragma unroll
        for (int mt = 0; mt < 4; mt++)
            af[mt] = *(const bf16x8*)&As[(wm + mt * 16 + l15) * 32 + q4 * 8];
        #pragma unroll
        for (int nt = 0; nt < 4; nt++)
            bf[nt] = *(const bf16x8*)&Bs[(wn + nt * 16 + l15) * 32 + q4 * 8];
        #pragma unroll
        for (int mt = 0; mt < 4; mt++)
            #pragma unroll
            for (int nt = 0; nt < 4; nt++)
                acc[mt][nt] = __builtin_amdgcn_mfma_f32_16x16x32_bf16(af[mt], bf[nt], acc[mt][nt], 0, 0, 0);
        __syncthreads();
    }
    #pragma unroll
    for (int nt = 0; nt < 4; nt++) {
        int gn = bn * 128 + wn + nt * 16 + l15;
        int d = gn >= NG ? 1 : 0;
        int col = gn - d * NG;
        float bias = biascat[gn];
        #pragma unroll
        for (int mt = 0; mt < 4; mt++) {
            #pragma unroll
            for (int r = 0; r < 4; r++) {
                int m = bm * 128 + wm + mt * 16 + q4 * 4 + r;
                int b = m / S2, t = m - b * S2;
                float v = acc[mt][nt][r] + bias;
                xg[((size_t)(d * NB + b) * S2 + t) * NG + col] = f2b(v);
            }
        }
    }
}

// ---------------- recurrence ----------------
// 32 WGs; cluster = (dir, batch-group) of 4 j-chunk WGs (blk%8 -> same-XCD heuristic).
// h exchange: SELF-VALIDATING TAGGED WORDS, u32 = (bf16_h << 16) | step_tag, in a
// 3-slot rotating buffer. Data and readiness are the same word: no flags, no fences,
// no vmcnt drains. Consumers poll-load and validate via a 24-word tag-sum (tags are
// monotone within a launch, buffer memset per launch).
// Coherence point chosen at runtime by a FUNCTIONAL probe: if all 4 WGs of a cluster
// can see each other's sc0 (L2-scope) stores, the whole cluster exchanges through the
// XCD L2 (~5x closer than the Infinity Cache); otherwise it uses sc0+sc1 (device
// scope). Consensus is reached through sc1 mask words, so a wrong co-location
// heuristic only costs speed, never correctness (Guideline 16).
__launch_bounds__(256, 1)
__global__ void k_recur(const u16* __restrict__ whhpack, const u16* __restrict__ xg,
                        const float* __restrict__ biascat, const u16* __restrict__ h0buf,
                        const float* __restrict__ c0, u16* __restrict__ hout,
                        int* __restrict__ flags, u32* __restrict__ xch) {
    const int blk = blockIdx.x;      // 0..31
    const int qc = blk >> 3;         // j-chunk 0..3
    const int cl = blk & 7;          // cluster id
    const int d = cl >> 2;           // direction
    const int g = cl & 3;            // batch group (16 batches)
    const int tid = threadIdx.x, lane = tid & 63, w = tid >> 6;  // wave = gate i,f,g,o
    const int q4 = lane >> 4, l15 = lane & 15;

    __shared__ float preact[4][16 * 96];
    __shared__ u16 hlds[16 * 104];   // own h chunk, padded stride 104 (bank spread)
    __shared__ int s_fast;

    // stationary Whh B-fragments, loaded in SIBLING-PERMUTED ks order so the MFMA
    // loops index bfr with compile-time constants: j=0..2 own chunk, 3..5 sib(qc+1),
    // 6..8 sib(qc+2), 9..11 sib(qc+3).
    bf16x8 bfr[6][12];
    #pragma unroll
    for (int nt = 0; nt < 6; nt++)
        #pragma unroll
        for (int j = 0; j < 12; j++) {
            int ksg = ((qc + (j / 3)) & 3) * 3 + (j % 3);
            bfr[nt][j] = *(const bf16x8*)(whhpack +
                ((size_t)((((d * 4 + qc) * 4 + w) * 6 + nt) * 12 + ksg) * 64 + lane) * 8);
        }

    // c-state in registers: 192 threads x 8 contiguous j-elements
    const int bb = tid / 12;              // batch within group (tid<192)
    const int j0 = (tid % 12) * 8;        // j offset within 96-chunk
    float cre[8];
    if (tid < 192) {
        const float* cp = c0 + (size_t)(d * NB + g * 16 + bb) * NH + qc * 96 + j0;
        #pragma unroll
        for (int e = 0; e < 8; e++) cre[e] = cp[e];
    }
    float biasreg[6];
    #pragma unroll
    for (int nt = 0; nt < 6; nt++)
        biasreg[nt] = biascat[d * NG + w * NH + qc * 96 + nt * 16 + l15];

    // ---- co-location probe + consensus (once per launch) ----
    if (tid == 0) {
        int* pzb = flags + cl * 64;          // probe words, 64B-line spread
        int* pmb = flags + 2048 + cl * 64;   // consensus masks
        st_sc0(pzb + qc * 16, MAGIC);
        u32 seen = 1u << qc;
        for (int spin = 0; spin < 512 && seen != 0xFu; ++spin) {
            #pragma unroll
            for (int r = 0; r < 4; ++r)
                if (!((seen >> r) & 1u) && ld_sc0(pzb + r * 16) == MAGIC) seen |= 1u << r;
            __builtin_amdgcn_s_sleep(2);
        }
        st_sc01(pmb + qc * 16, (int)(0x100u | seen));
        u32 m = 0xFu;
        #pragma unroll
        for (int r = 0; r < 4; ++r) {
            u32 v;
            do { v = ld_sc01(pmb + r * 16); } while (!(v & 0x100u));
            m &= v;
        }
        s_fast = ((m & 0xFu) == 0xFu) ? 1 : 0;
    }
    __syncthreads();
    const bool fast = (s_fast != 0);

    const u16* xgd = xg + (size_t)d * NB * S2 * NG;

    float ci[6][4];
    auto preload = [&](int it2) {
        int s2 = d ? (NS - 1 - it2) : it2;
        if (s2 < S2) {
            const u16* xrow = xgd + ((size_t)(g * 16) * S2 + s2) * NG + w * NH + qc * 96 + l15;
            #pragma unroll
            for (int nt = 0; nt < 6; nt++)
                #pragma unroll
                for (int r = 0; r < 4; r++)
                    ci[nt][r] = b2f(xrow[(size_t)(q4 * 4 + r) * S2 * NG + nt * 16]);
        } else {
            #pragma unroll
            for (int nt = 0; nt < 6; nt++)
                #pragma unroll
                for (int r = 0; r < 4; r++) ci[nt][r] = biasreg[nt];
        }
    };
    preload(0);

    #pragma unroll 1
    for (int it = 0; it < NS; ++it) {
        int s = d ? (NS - 1 - it) : it;
        f32x4 acc[6];

        if (it == 0) {
            bf16x8 af0[12];
            const u16* hp = h0buf + (size_t)(d * NB + g * 16) * NH;
            #pragma unroll
            for (int j = 0; j < 12; j++) {
                int ksg = ((qc + (j / 3)) & 3) * 3 + (j % 3);
                af0[j] = *(const bf16x8*)(hp + (size_t)l15 * NH + ksg * 32 + q4 * 8);
            }
            #pragma unroll
            for (int nt = 0; nt < 6; nt++) {
                acc[nt][0] = ci[nt][0]; acc[nt][1] = ci[nt][1];
                acc[nt][2] = ci[nt][2]; acc[nt][3] = ci[nt][3];
            }
            preload(1);
            #pragma unroll
            for (int j = 0; j < 12; j++)
                #pragma unroll
                for (int nt = 0; nt < 6; nt++)
                    acc[nt] = __builtin_amdgcn_mfma_f32_16x16x32_bf16(af0[j], bfr[nt][j], acc[nt], 0, 0, 0);
        } else {
            // own chunk from LDS (never leaves the CU)
            bf16x8 afo0 = *(const bf16x8*)&hlds[l15 * 104 + 0 * 32 + q4 * 8];
            bf16x8 afo1 = *(const bf16x8*)&hlds[l15 * 104 + 1 * 32 + q4 * 8];
            bf16x8 afo2 = *(const bf16x8*)&hlds[l15 * 104 + 2 * 32 + q4 * 8];
            const u32 T = (u32)it;
            const u32 want = T * 24u;
            u32* xrow = xch + (((size_t)(T % 3u) * 8 + cl) * 16 + l15) * 384 + q4 * 8;
            u32* pA = xrow + ((qc + 1) & 3) * 96;
            u32* pB = xrow + ((qc + 2) & 3) * 96;
            u32* pC = xrow + ((qc + 3) & 3) * 96;
            u32x4 a0, a1, a2, a3, a4, a5, b0, b1, b2, b3, b4, b5, e0, e1, e2, e3, e4, e5;
            ld6_nw(fast, pA, a0, a1, a2, a3, a4, a5);
            ld6_nw(fast, pB, b0, b1, b2, b3, b4, b5);
            #pragma unroll
            for (int nt = 0; nt < 6; nt++) {
                acc[nt][0] = ci[nt][0]; acc[nt][1] = ci[nt][1];
                acc[nt][2] = ci[nt][2]; acc[nt][3] = ci[nt][3];
            }
            // own-chunk MFMAs cover sibling-A load latency
            #pragma unroll
            for (int nt = 0; nt < 6; nt++)
                acc[nt] = __builtin_amdgcn_mfma_f32_16x16x32_bf16(afo0, bfr[nt][0], acc[nt], 0, 0, 0);
            #pragma unroll
            for (int nt = 0; nt < 6; nt++)
                acc[nt] = __builtin_amdgcn_mfma_f32_16x16x32_bf16(afo1, bfr[nt][1], acc[nt], 0, 0, 0);
            #pragma unroll
            for (int nt = 0; nt < 6; nt++)
                acc[nt] = __builtin_amdgcn_mfma_f32_16x16x32_bf16(afo2, bfr[nt][2], acc[nt], 0, 0, 0);
            wait_vm6();   // A done (B still may be in flight)
            while (!__all(sum6(a0, a1, a2, a3, a4, a5) == want))
                ld6_wt(fast, pA, a0, a1, a2, a3, a4, a5);
            bf16x8 afA0 = packf(a0, a1), afA1 = packf(a2, a3), afA2 = packf(a4, a5);
            ld6_nw(fast, pC, e0, e1, e2, e3, e4, e5);
            #pragma unroll
            for (int nt = 0; nt < 6; nt++)
                acc[nt] = __builtin_amdgcn_mfma_f32_16x16x32_bf16(afA0, bfr[nt][3], acc[nt], 0, 0, 0);
            #pragma unroll
            for (int nt = 0; nt < 6; nt++)
                acc[nt] = __builtin_amdgcn_mfma_f32_16x16x32_bf16(afA1, bfr[nt][4], acc[nt], 0, 0, 0);
            #pragma unroll
            for (int nt = 0; nt < 6; nt++)
                acc[nt] = __builtin_amdgcn_mfma_f32_16x16x32_bf16(afA2, bfr[nt][5], acc[nt], 0, 0, 0);
            wait_vm6();   // B done
            while (!__all(sum6(b0, b1, b2, b3, b4, b5) == want))
                ld6_wt(fast, pB, b0, b1, b2, b3, b4, b5);
            bf16x8 afB0 = packf(b0, b1), afB1 = packf(b2, b3), afB2 = packf(b4, b5);
            #pragma unroll
            for (int nt = 0; nt < 6; nt++)
                acc[nt] = __builtin_amdgcn_mfma_f32_16x16x32_bf16(afB0, bfr[nt][6], acc[nt], 0, 0, 0);
            #pragma unroll
            for (int nt = 0; nt < 6; nt++)
                acc[nt] = __builtin_amdgcn_mfma_f32_16x16x32_bf16(afB1, bfr[nt][7], acc[nt], 0, 0, 0);
            #pragma unroll
            for (int nt = 0; nt < 6; nt++)
                acc[nt] = __builtin_amdgcn_mfma_f32_16x16x32_bf16(afB2, bfr[nt][8], acc[nt], 0, 0, 0);
            wait_vm0();   // C done
            while (!__all(sum6(e0, e1, e2, e3, e4, e5) == want))
                ld6_wt(fast, pC, e0, e1, e2, e3, e4, e5);
            bf16x8 afC0 = packf(e0, e1), afC1 = packf(e2, e3), afC2 = packf(e4, e5);
            if (it + 1 < NS) preload(it + 1);   // after last poll wait: HBM latency never lands in a poll
            #pragma unroll
            for (int nt = 0; nt < 6; nt++)
                acc[nt] = __builtin_amdgcn_mfma_f32_16x16x32_bf16(afC0, bfr[nt][9], acc[nt], 0, 0, 0);
            #pragma unroll
            for (int nt = 0; nt < 6; nt++)
                acc[nt] = __builtin_amdgcn_mfma_f32_16x16x32_bf16(afC1, bfr[nt][10], acc[nt], 0, 0, 0);
            #pragma unroll
            for (int nt = 0; nt < 6; nt++)
                acc[nt] = __builtin_amdgcn_mfma_f32_16x16x32_bf16(afC2, bfr[nt][11], acc[nt], 0, 0, 0);
        }

        // preact (this wave's gate) -> LDS
        #pragma unroll
        for (int nt = 0; nt < 6; nt++)
            #pragma unroll
            for (int r = 0; r < 4; r++)
                preact[w][(q4 * 4 + r) * 96 + nt * 16 + l15] = acc[nt][r];
        ldsbar();

        // cell update: 192 threads x 8 contiguous elements
        if (tid < 192) {
            int idx = bb * 96 + j0;
            u16* ho = hout + (((size_t)(d * NB + g * 16 + bb)) * NS + s) * NH + qc * 96 + j0;
            union { u16 u[8]; u32x4 v4; } pk;
            #pragma unroll
            for (int e = 0; e < 8; e++) {
                float gi = preact[0][idx + e], gf = preact[1][idx + e];
                float gg = preact[2][idx + e], go = preact[3][idx + e];
                float c = cre[e];
                float cn = sigm(gf) * c + sigm(gi) * tanh_(gg);
                float hn = sigm(go) * tanh_(cn);
                cre[e] = cn;
                pk.u[e] = f2b(hn);
            }
            *(u32x4*)ho = pk.v4;                       // output history (plain, cached)
            *(u32x4*)&hlds[bb * 104 + j0] = pk.v4;     // own chunk for next step
            u32 t2 = (u32)it + 1u;
            u32x4 lo, hi;
            lo[0] = ((u32)pk.u[0] << 16) | t2; lo[1] = ((u32)pk.u[1] << 16) | t2;
            lo[2] = ((u32)pk.u[2] << 16) | t2; lo[3] = ((u32)pk.u[3] << 16) | t2;
            hi[0] = ((u32)pk.u[4] << 16) | t2; hi[1] = ((u32)pk.u[5] << 16) | t2;
            hi[2] = ((u32)pk.u[6] << 16) | t2; hi[3] = ((u32)pk.u[7] << 16) | t2;
            u32* xp = xch + (((size_t)(t2 % 3u) * 8 + cl) * 16 + bb) * 384 + qc * 96 + j0;
            st8(fast, xp, lo, hi);                     // tagged publish, fire-and-forget
        }
        ldsbar();
    }
}

// ---------------- final linear: out[b,t,22] = [hf|hb] @ WlinT + blin ----------------
__global__ void k_final(const u16* __restrict__ hout, const float* __restrict__ wlin,
                        const float* __restrict__ blin, float* __restrict__ out) {
    int r = blockIdx.x * 256 + threadIdx.x;   // 0..32767
    int b = r >> 9, t = r & 511;
    const u16* hf = hout + ((size_t)b * NS + t) * NH;
    const u16* hb = hout + ((size_t)(NB + b) * NS + t) * NH;
    float acc[NT_OUT];
    #pragma unroll
    for (int tt = 0; tt < NT_OUT; tt++) acc[tt] = blin[tt];
    #pragma unroll 1
    for (int half = 0; half < 2; half++) {
        const u16* hp = half ? hb : hf;
        #pragma unroll 1
        for (int k8 = 0; k8 < NH / 8; k8++) {
            uint4 pk = *(const uint4*)(hp + k8 * 8);
            float x[8];
            x[0] = __uint_as_float(pk.x << 16); x[1] = __uint_as_float(pk.x & 0xffff0000u);
            x[2] = __uint_as_float(pk.y << 16); x[3] = __uint_as_float(pk.y & 0xffff0000u);
            x[4] = __uint_as_float(pk.z << 16); x[5] = __uint_as_float(pk.z & 0xffff0000u);
            x[6] = __uint_as_float(pk.w << 16); x[7] = __uint_as_float(pk.w & 0xffff0000u);
            int kk = half * NH + k8 * 8;
            #pragma unroll
            for (int e = 0; e < 8; e++)
                #pragma unroll
                for (int tt = 0; tt < NT_OUT; tt++)
                    acc[tt] += x[e] * wlin[tt * (2 * NH) + kk + e];   // uniform -> s_load
        }
    }
    float* op = out + (size_t)r * NT_OUT;
    #pragma unroll
    for (int tt = 0; tt < NT_OUT; tt++) op[tt] = acc[tt];
}

extern "C" void kernel_launch(void* const* d_in, const int* in_sizes, int n_in,
                              void* d_out, int out_size, void* d_ws, size_t ws_size,
                              hipStream_t stream) {
    const float* hidden = (const float*)d_in[0];
    const float* h0     = (const float*)d_in[1];
    const float* c0     = (const float*)d_in[2];
    const float* Wihf   = (const float*)d_in[3];
    const float* Whhf   = (const float*)d_in[4];
    const float* bihf   = (const float*)d_in[5];
    const float* bhhf   = (const float*)d_in[6];
    const float* Wihb   = (const float*)d_in[7];
    const float* Whhb   = (const float*)d_in[8];
    const float* bihb   = (const float*)d_in[9];
    const float* bhhb   = (const float*)d_in[10];
    const float* Wlin   = (const float*)d_in[11];
    const float* blin   = (const float*)d_in[12];
    const int* start_ids = (const int*)d_in[13];
    const int* masks     = (const int*)d_in[14];
    float* out = (float*)d_out;

    char* ws = (char*)d_ws;
    size_t off = 0;
    auto alloc = [&](size_t bytes) { void* p = ws + off; off += (bytes + 255) & ~(size_t)255; return p; };
    u16* embeds   = (u16*)alloc((size_t)MGEMM * ND * 2);           // 26.7 MB
    u16* wihcat   = (u16*)alloc((size_t)2 * NG * ND * 2);          // 4.7 MB
    float* biascat = (float*)alloc((size_t)2 * NG * 4);            // 12 KB
    u16* whhpack  = (u16*)alloc((size_t)2 * NG * NH * 2);          // 2.36 MB
    u16* h0buf    = (u16*)alloc((size_t)2 * NB * NH * 2);          // 98 KB
    u16* xg       = (u16*)alloc((size_t)2 * NB * S2 * NG * 2);     // 107 MB
    u16* hout     = (u16*)alloc((size_t)2 * NB * NS * NH * 2);     // 50.3 MB
    int* flags    = (int*)alloc((size_t)8 * NS * 4);               // 16 KB (probe+consensus)
    u32* xch      = (u32*)alloc((size_t)3 * 8 * 16 * 384 * 4);     // 576 KB tagged h exchange

    (void)hipMemsetAsync(flags, 0, (size_t)8 * NS * 4, stream);
    (void)hipMemsetAsync(xch, 0, (size_t)3 * 8 * 16 * 384 * 4, stream);
    k_prep<<<256, 256, 0, stream>>>(hidden, start_ids, masks, embeds);
    k_weights<<<512, 256, 0, stream>>>(Wihf, Wihb, bihf, bhhf, bihb, bhhb, h0,
                                       wihcat, biascat, h0buf);
    k_packwhh<<<576, 256, 0, stream>>>(Whhf, Whhb, whhpack);
    dim3 ggrid(2 * NG / 128, MGEMM / 128);
    k_gemm<<<ggrid, 256, 0, stream>>>(embeds, wihcat, biascat, xg);
    k_recur<<<32, 256, 0, stream>>>(whhpack, xg, biascat, h0buf, c0, hout, flags, xch);
    k_final<<<128, 256, 0, stream>>>(hout, Wlin, blin, out);
}